// Round 3
// baseline (231.810 us; speedup 1.0000x reference)
//
#include <hip/hip_runtime.h>

// x: [B=64, C=12, 224, 224] f32; w: [C=12, E=768] f32
// out[b, i*14+j, e] = sum_c (16x16 patch-sum of x[b,c]) * w[c,e]
// Memory-bound: 154 MB read + 38.5 MB write -> ~31 us @ 6.3 TB/s.
// R2: block = 32x32 region (4 patches). 8 independent loads/thread keeps more
// HBM requests in flight per wave; reduce/barrier/epilogue tail amortized 2x.

#define BATCH 64
#define CH    12
#define IMGD  224
#define NP    14          // patches per side
#define NPP   (NP * NP)   // 196
#define EMB   768
#define E4    (EMB / 4)   // 192 float4 per output row

__global__ __launch_bounds__(384) void dcsp_fused_kernel(
    const float* __restrict__ x,
    const float* __restrict__ w,
    float* __restrict__ out)
{
    // grid: b * 49 + ii*7 + jj ; block covers rows [32ii,32ii+32), cols [32jj,32jj+32)
    const int blk = blockIdx.x;
    const int b  = blk / ((NP / 2) * (NP / 2));
    const int r0 = blk - b * ((NP / 2) * (NP / 2));
    const int ii = r0 / (NP / 2);
    const int jj = r0 - ii * (NP / 2);

    const int t    = threadIdx.x;        // 0..383
    const int lane = t & 63;
    const int wave = t >> 6;             // 0..5 -> channels 2w, 2w+1

    __shared__ float pooled[2][2][CH];   // [vert][horiz][channel]

    // lane -> (row-octet r8 = lane>>3, col-quad q = lane&7); 8 lanes = one 128B line
    const int r8 = lane >> 3;
    const int q  = lane & 7;
    const int colbase = jj * 32 + q * 4;

    // s[k][v]: channel 2*wave+k, vertical half v (top patches / bottom patches)
    float s[2][2] = {{0.f, 0.f}, {0.f, 0.f}};
#pragma unroll
    for (int k = 0; k < 2; ++k) {
        const int c = wave * 2 + k;
        const size_t chbase = (size_t)(b * CH + c) * IMGD * IMGD;
#pragma unroll
        for (int half = 0; half < 4; ++half) {   // 4 row-octets = 32 rows
            const int row = ii * 32 + half * 8 + r8;
            const float4 v = *reinterpret_cast<const float4*>(
                x + chbase + (size_t)row * IMGD + colbase);
            s[k][half >> 1] += (v.x + v.y) + (v.z + v.w);
        }
    }

    // xor-shuffle reduce over masks {1,2,8,16,32}; preserves lane bit 2
    // (q<4 = left patch cols, q>=4 = right patch cols)
#pragma unroll
    for (int m = 0; m < 5; ++m) {
        const int mask = (1 << m) < 4 ? (1 << m) : (1 << (m + 1));
#pragma unroll
        for (int k = 0; k < 2; ++k)
#pragma unroll
            for (int v = 0; v < 2; ++v)
                s[k][v] += __shfl_xor(s[k][v], mask, 64);
    }
    if (lane == 0 || lane == 4) {
        const int h = lane >> 2;         // 0 = left, 1 = right
#pragma unroll
        for (int k = 0; k < 2; ++k) {
            pooled[0][h][wave * 2 + k] = s[k][0];
            pooled[1][h][wave * 2 + k] = s[k][1];
        }
    }
    __syncthreads();

    // 4 patches x 192 float4 = 768 outputs; 384 threads do 2 each
    const float4* __restrict__ w4 = reinterpret_cast<const float4*>(w);
#pragma unroll
    for (int rep = 0; rep < 2; ++rep) {
        const int idx   = t + rep * 384;     // 0..767
        const int patch = idx / E4;          // 0..3 : (vert<<1)|horiz
        const int e4    = idx - patch * E4;
        const int pv    = patch >> 1;
        const int ph    = patch & 1;

        float4 acc = make_float4(0.f, 0.f, 0.f, 0.f);
#pragma unroll
        for (int c = 0; c < CH; ++c) {
            const float  pc = pooled[pv][ph][c];
            const float4 wv = w4[c * E4 + e4];
            acc.x += pc * wv.x;
            acc.y += pc * wv.y;
            acc.z += pc * wv.z;
            acc.w += pc * wv.w;
        }
        const int i = ii * 2 + pv;
        const int j = jj * 2 + ph;
        reinterpret_cast<float4*>(out)[((size_t)(b * NPP) + i * NP + j) * E4 + e4] = acc;
    }
}

extern "C" void kernel_launch(void* const* d_in, const int* in_sizes, int n_in,
                              void* d_out, int out_size, void* d_ws, size_t ws_size,
                              hipStream_t stream) {
    const float* x = (const float*)d_in[0];
    const float* w = (const float*)d_in[1];
    float* out = (float*)d_out;

    dcsp_fused_kernel<<<BATCH * (NP / 2) * (NP / 2), 384, 0, stream>>>(x, w, out);
}

// Round 4
// 231.712 us; speedup vs baseline: 1.0004x; 1.0004x over previous
//
#include <hip/hip_runtime.h>

// x: [B=64, C=12, 224, 224] f32; w: [C=12, E=768] f32
// out[b, i*14+j, e] = sum_c (16x16 patch-sum of x[b,c]) * w[c,e]
// Roofline: 154 MB read + 38.5 MB write ~= 31 us @ 6.3 TB/s.
// R3: split into two pure streaming kernels.
//   A: pool.  block = (b,c,i) strip, 14 KB fully-contiguous read, LDS tree
//      reduce -> pooled[64,12,14,14] in d_ws (614 KB).
//   B: matmul. w columns register-resident per block (kills the 450 MB of
//      repeated w L2 traffic the fused kernel had), 14 patches per block,
//      contiguous 3 KB row stores. Pure write-streaming.

#define BATCH 64
#define CH    12
#define IMGD  224
#define NP    14
#define NPP   (NP * NP)      // 196
#define EMB   768
#define E4    (EMB / 4)      // 192

// ---------------- Kernel A: sum-pool ----------------
// grid = B*C*NP = 10752 blocks of 256. Block bci covers strip rows
// [16i,16i+16) of channel (b,c): 16*224 floats = 896 float4, contiguous.
__global__ __launch_bounds__(256) void pool_kernel(
    const float* __restrict__ x, float* __restrict__ pooled)
{
    const int bci = blockIdx.x;                    // (b*CH + c)*NP + i
    const int t   = threadIdx.x;

    __shared__ float part[896];                    // per-float4 partial sums
    __shared__ float p2[NP * 16];                  // per-(j,row) partials

    const float4* __restrict__ x4 =
        reinterpret_cast<const float4*>(x) + (size_t)bci * 896;

    // 896 contiguous float4 loads by 256 threads (3.5 iterations)
    {
        float4 a = x4[t];
        float4 b = x4[t + 256];
        float4 c = x4[t + 512];
        part[t]       = (a.x + a.y) + (a.z + a.w);
        part[t + 256] = (b.x + b.y) + (b.z + b.w);
        part[t + 512] = (c.x + c.y) + (c.z + c.w);
        if (t < 128) {
            float4 d = x4[t + 768];
            part[t + 768] = (d.x + d.y) + (d.z + d.w);
        }
    }
    __syncthreads();

    // stage 1: one thread per (j, r): sum the 4 chunks of patch j in row r
    if (t < NP * 16) {
        const int j = t >> 4, r = t & 15;
        const int o = r * 56 + j * 4;              // 56 float4-chunks per row
        p2[t] = (part[o] + part[o + 1]) + (part[o + 2] + part[o + 3]);
    }
    __syncthreads();

    // stage 2: one thread per patch j: sum 16 rows, store
    if (t < NP) {
        float s = 0.f;
#pragma unroll
        for (int r = 0; r < 16; ++r) s += p2[t * 16 + r];
        pooled[(size_t)bci * NP + t] = s;          // = b*2352 + c*196 + i*14 + j
    }
}

// ---------------- Kernel B: C->E matmul, write-streaming ----------------
// grid = 896 blocks of 192; each block does 14 patch-rows (896*14 = 12544).
// Thread t owns output column float4 e4=t; w column slice lives in registers.
__global__ __launch_bounds__(192) void mm_kernel(
    const float* __restrict__ pooled, const float* __restrict__ w,
    float* __restrict__ out)
{
    const int t = threadIdx.x;                     // 0..191 = e4
    const float4* __restrict__ w4 = reinterpret_cast<const float4*>(w);

    float4 wc[CH];
#pragma unroll
    for (int c = 0; c < CH; ++c) wc[c] = w4[c * E4 + t];

    float4* __restrict__ o4 = reinterpret_cast<float4*>(out);

    for (int bp = blockIdx.x; bp < BATCH * NPP; bp += gridDim.x) {
        const int b = bp / NPP;
        const int p = bp - b * NPP;
        const float* __restrict__ pv = pooled + (size_t)b * (CH * NPP) + p;

        float pc[CH];
#pragma unroll
        for (int c = 0; c < CH; ++c) pc[c] = pv[c * NPP];   // wave-uniform loads

        float4 acc = make_float4(0.f, 0.f, 0.f, 0.f);
#pragma unroll
        for (int c = 0; c < CH; ++c) {
            acc.x += pc[c] * wc[c].x;
            acc.y += pc[c] * wc[c].y;
            acc.z += pc[c] * wc[c].z;
            acc.w += pc[c] * wc[c].w;
        }
        o4[(size_t)bp * E4 + t] = acc;             // contiguous 3 KB row
    }
}

extern "C" void kernel_launch(void* const* d_in, const int* in_sizes, int n_in,
                              void* d_out, int out_size, void* d_ws, size_t ws_size,
                              hipStream_t stream) {
    const float* x = (const float*)d_in[0];
    const float* w = (const float*)d_in[1];
    float* out    = (float*)d_out;
    float* pooled = (float*)d_ws;                  // 64*12*196 floats = 614 KB

    pool_kernel<<<BATCH * CH * NP, 256, 0, stream>>>(x, pooled);
    mm_kernel<<<896, 192, 0, stream>>>(pooled, w, out);
}

// Round 6
// 222.068 us; speedup vs baseline: 1.0439x; 1.0434x over previous
//
#include <hip/hip_runtime.h>

// x: [B=64, C=12, 224, 224] f32; w: [C=12, E=768] f32
// out[b, i*14+j, e] = sum_c (16x16 patch-sum of x[b,c]) * w[c,e]
// Roofline: 154 MB read + 38.5 MB write ~= 31 us @ 6.3 TB/s.
// R5 = R4 with the compile fix: __builtin_nontemporal_* needs a clang
// ext_vector_type pointer, not HIP's float4 class. Theory unchanged: poison
// fills leave L3 dirty -> our cold misses pay dirty-eviction writebacks; nt
// bits skip L2/L3 allocation. w stays cacheable (reused by all blocks).

#define BATCH 64
#define CH    12
#define IMGD  224
#define NP    14          // patches per side
#define NPP   (NP * NP)   // 196
#define EMB   768
#define E4    (EMB / 4)   // 192 float4 per output row

typedef float vfloat4 __attribute__((ext_vector_type(4)));

__global__ __launch_bounds__(384) void dcsp_fused_kernel(
    const float* __restrict__ x,
    const float* __restrict__ w,
    float* __restrict__ out)
{
    // grid: b * (14*7) + i*7 + jj   (jj = patch-pair index, covers j=2jj, 2jj+1)
    const int blk = blockIdx.x;
    const int b  = blk / (NP * (NP / 2));
    const int r0 = blk - b * (NP * (NP / 2));
    const int i  = r0 / (NP / 2);
    const int jj = r0 - i * (NP / 2);

    const int t    = threadIdx.x;        // 0..383
    const int lane = t & 63;
    const int wave = t >> 6;             // 0..5

    __shared__ float pooled[2][CH];      // [left/right patch][channel]

    // lane -> (row-octet, col-quad) inside the 16x32 region:
    //   r8 = lane>>3 (0..7 rows), q = lane&7 (8 quads = one 128 B line)
    const int r8 = lane >> 3;
    const int q  = lane & 7;
    const int colbase = jj * 32 + q * 4;

    // wave w handles channels 2w and 2w+1; two half-region loads each
    float s[2] = {0.f, 0.f};
#pragma unroll
    for (int k = 0; k < 2; ++k) {
        const int c = wave * 2 + k;
        const size_t chbase = (size_t)(b * CH + c) * IMGD * IMGD;
#pragma unroll
        for (int half = 0; half < 2; ++half) {
            const int row = i * 16 + half * 8 + r8;
            const vfloat4 v = __builtin_nontemporal_load(
                reinterpret_cast<const vfloat4*>(
                    x + chbase + (size_t)row * IMGD + colbase));
            s[k] += (v.x + v.y) + (v.z + v.w);
        }
    }

    // xor-shuffle reduce over masks {1,2,8,16,32}: sums the 32 lanes sharing
    // lane-bit 2 (q<4 = left patch, q>=4 = right patch)
#pragma unroll
    for (int m = 0; m < 5; ++m) {
        const int mask = (1 << m) < 4 ? (1 << m) : (1 << (m + 1)); // 1,2,8,16,32
#pragma unroll
        for (int k = 0; k < 2; ++k)
            s[k] += __shfl_xor(s[k], mask, 64);
    }
    if (lane == 0) {
        pooled[0][wave * 2 + 0] = s[0];
        pooled[0][wave * 2 + 1] = s[1];
    } else if (lane == 4) {
        pooled[1][wave * 2 + 0] = s[0];
        pooled[1][wave * 2 + 1] = s[1];
    }
    __syncthreads();

    // 384 threads -> 2 patches x 192 float4 outputs
    const int patch = t / E4;            // 0 = left (j=2jj), 1 = right
    const int e4    = t - patch * E4;

    vfloat4 acc = (vfloat4){0.f, 0.f, 0.f, 0.f};
    const vfloat4* __restrict__ w4 = reinterpret_cast<const vfloat4*>(w);
#pragma unroll
    for (int c = 0; c < CH; ++c) {
        const float   pc = pooled[patch][c];
        const vfloat4 wv = w4[c * E4 + e4];
        acc += pc * wv;
    }
    const int j = jj * 2 + patch;
    vfloat4* o4 = reinterpret_cast<vfloat4*>(out) +
                  (((size_t)(b * NPP) + i * NP + j) * E4 + e4);
    __builtin_nontemporal_store(acc, o4);
}

extern "C" void kernel_launch(void* const* d_in, const int* in_sizes, int n_in,
                              void* d_out, int out_size, void* d_ws, size_t ws_size,
                              hipStream_t stream) {
    const float* x = (const float*)d_in[0];
    const float* w = (const float*)d_in[1];
    float* out = (float*)d_out;

    dcsp_fused_kernel<<<BATCH * NP * (NP / 2), 384, 0, stream>>>(x, w, out);
}